// Round 5
// baseline (531.846 us; speedup 1.0000x reference)
//
#include <hip/hip_runtime.h>
#include <hip/hip_bf16.h>

typedef float ff4 __attribute__((ext_vector_type(4)));
typedef short s8v __attribute__((ext_vector_type(8)));
typedef unsigned int u4v __attribute__((ext_vector_type(4)));

#define Hd 1024
#define Nn 256
#define KC 32
#define NCHUNK 32

__device__ __forceinline__ unsigned bf16r(float f) {
    unsigned u = __builtin_bit_cast(unsigned, f);
    return (u + 0x7FFFu + ((u >> 16) & 1u)) >> 16;   // RNE f32->bf16
}

__device__ __forceinline__ unsigned cvtpk(float lo, float hi) {
    unsigned r;
    asm("v_cvt_pk_bf16_f32 %0, %1, %2" : "=v"(r) : "v"(lo), "v"(hi));
    return r;
}

__device__ __forceinline__ void glds16(void* lds, const void* g) {
    __builtin_amdgcn_global_load_lds(
        (const __attribute__((address_space(1))) unsigned int*)g,
        (__attribute__((address_space(3))) unsigned int*)lds, 16, 0, 0);
}

// ---- memB: chunk-major KC=32, 16B-block swizzled:
// byte(c,r,b) at c*16384 + r*64 + ((b ^ ((r>>1)&3))*16) = bf16(mem[r][c*32 + b*8 .. +8])
__global__ void conv_mem_kernel(const float* __restrict__ mem, unsigned short* __restrict__ memB) {
    int g = blockIdx.x * 256 + threadIdx.x;   // 0..32767
    int b = g & 3;
    int r = (g >> 2) & 255;
    int c = g >> 10;
    const float* src = mem + (size_t)r * Hd + c * KC + b * 8;
    ff4 a0 = *(const ff4*)src;
    ff4 a1 = *(const ff4*)(src + 4);
    u4v v;
    v[0] = bf16r(a0[0]) | (bf16r(a0[1]) << 16);
    v[1] = bf16r(a0[2]) | (bf16r(a0[3]) << 16);
    v[2] = bf16r(a1[0]) | (bf16r(a1[1]) << 16);
    v[3] = bf16r(a1[2]) | (bf16r(a1[3]) << 16);
    size_t dst = (size_t)c * 16384 + (size_t)r * 64 + (size_t)((b ^ ((r >> 1) & 3)) * 16);
    *(u4v*)((char*)memB + dst) = v;
}

// ---- Wbf[c][h] = bf16(Wout[h][c]), c in {0,1} ----
__global__ void conv_w_kernel(const float* __restrict__ Wout, unsigned short* __restrict__ Wbf) {
    int t = threadIdx.x;
    int c = t >> 7;
    int h0 = (t & 127) * 8;
    u4v v;
#pragma unroll
    for (int j = 0; j < 4; ++j) {
        unsigned lo = bf16r(Wout[(h0 + 2 * j) * 2 + c]);
        unsigned hi = bf16r(Wout[(h0 + 2 * j + 1) * 2 + c]);
        v[j] = lo | (hi << 16);
    }
    *(u4v*)(Wbf + (size_t)c * Hd + h0) = v;
}

// ---- Gram matrix G = mem @ mem^T  [256][256], bf16 ----
__global__ __launch_bounds__(256) void gram_kernel(const float* __restrict__ mem,
                                                   unsigned short* __restrict__ Gbf) {
    __shared__ float LA[32][132];
    __shared__ float LB[32][132];
    const int t = threadIdx.x;
    const int bi = blockIdx.x >> 3, bj = blockIdx.x & 7;
    const int j = t & 31, i0 = t >> 5;
    float acc0 = 0.f, acc1 = 0.f, acc2 = 0.f, acc3 = 0.f;
    for (int kc = 0; kc < Hd; kc += 128) {
        __syncthreads();
#pragma unroll
        for (int q = 0; q < 4; ++q) {
            int c = t + q * 256;
            int r = c >> 5, fc = (c & 31) << 2;
            *(ff4*)&LA[r][fc] = *(const ff4*)(mem + (size_t)(bi * 32 + r) * Hd + kc + fc);
            *(ff4*)&LB[r][fc] = *(const ff4*)(mem + (size_t)(bj * 32 + r) * Hd + kc + fc);
        }
        __syncthreads();
#pragma unroll 4
        for (int kk = 0; kk < 128; kk += 4) {
            ff4 b = *(const ff4*)&LB[j][kk];
            ff4 a0 = *(const ff4*)&LA[i0][kk];
            ff4 a1 = *(const ff4*)&LA[i0 + 8][kk];
            ff4 a2 = *(const ff4*)&LA[i0 + 16][kk];
            ff4 a3 = *(const ff4*)&LA[i0 + 24][kk];
            acc0 += a0[0]*b[0] + a0[1]*b[1] + a0[2]*b[2] + a0[3]*b[3];
            acc1 += a1[0]*b[0] + a1[1]*b[1] + a1[2]*b[2] + a1[3]*b[3];
            acc2 += a2[0]*b[0] + a2[1]*b[1] + a2[2]*b[2] + a2[3]*b[3];
            acc3 += a3[0]*b[0] + a3[1]*b[1] + a3[2]*b[2] + a3[3]*b[3];
        }
    }
    const int gj = bj * 32 + j;
    Gbf[(size_t)(bi * 32 + i0 +  0) * Nn + gj] = (unsigned short)bf16r(acc0);
    Gbf[(size_t)(bi * 32 + i0 +  8) * Nn + gj] = (unsigned short)bf16r(acc1);
    Gbf[(size_t)(bi * 32 + i0 + 16) * Nn + gj] = (unsigned short)bf16r(acc2);
    Gbf[(size_t)(bi * 32 + i0 + 24) * Nn + gj] = (unsigned short)bf16r(acc3);
}

// ---- fused main kernel: 64 rows/block, 4 waves, 1 barrier/body, counted vmcnt ----
__global__ __launch_bounds__(256, 3) void fused_kernel(
    const float* __restrict__ user, const float* __restrict__ music,
    const float* __restrict__ bout, const int* __restrict__ label,
    const unsigned short* __restrict__ memB,   // [32][256][32] bf16, block-swizzled
    const unsigned short* __restrict__ Wbf,    // [2][1024] bf16
    const unsigned short* __restrict__ Gbf,    // [256][256] bf16
    float* __restrict__ out, float* __restrict__ partials)
{
    __shared__ __align__(16) unsigned char smem[32768];   // 2 x 16384 sM dbuf; epilogue attn alias
    unsigned short* sAttn = (unsigned short*)smem;

    const int t = threadIdx.x;
    const int w = t >> 6;
    const int l = t & 63;
    const int la = l & 15, lb = l >> 4;
    const int row0 = blockIdx.x * 64;
    const int myrow = row0 + w * 16 + la;

    const float* uR = user  + (size_t)myrow * Hd + lb * 8;
    const float* mR = music + (size_t)myrow * Hd + lb * 8;
    const char* gsrcW = (const char*)memB + w * 4096 + l * 16;
    const unsigned short* wrowB = Wbf + (size_t)(la < 2 ? la : 1) * Hd + lb * 8;
    const int myoff = la * 64 + ((lb ^ ((la >> 1) & 3)) << 4);

    ff4 accL[16], accD[16];
#pragma unroll
    for (int i = 0; i < 16; ++i) { accL[i] = (ff4)0.0f; accD[i] = (ff4)0.0f; }
    ff4 accH = (ff4)0.0f;
    float sd2 = 0.f;

    // ---- prologue: issue chunk 0 (glds -> buf0, um -> regs, bW -> regs) ----
#pragma unroll
    for (int i = 0; i < 4; ++i)
        glds16(smem + w * 4096 + i * 1024, gsrcW + i * 1024);
    ff4 ua = *(const ff4*)(uR);
    ff4 ub = *(const ff4*)(uR + 4);
    ff4 ma = *(const ff4*)(mR);
    ff4 mb = *(const ff4*)(mR + 4);
    s8v bW = *(const s8v*)(wrowB);
    __builtin_amdgcn_sched_barrier(0);

    for (int c = 0; c < NCHUNK; ++c) {
        const int bsel = c & 1;
        // glds(c) landed?  outstanding: glds(c)x4 (oldest), um(c)x4, bW(c)x1
        asm volatile("s_waitcnt vmcnt(5)" ::: "memory");
        __builtin_amdgcn_s_barrier();
        __builtin_amdgcn_sched_barrier(0);

        // cvt um(c) -> frags (compiler inserts counted vmcnt for um regs)
        float s0 = ua[0]*ma[0], s1 = ua[1]*ma[1], s2 = ua[2]*ma[2], s3 = ua[3]*ma[3];
        float s4 = ub[0]*mb[0], s5 = ub[1]*mb[1], s6 = ub[2]*mb[2], s7 = ub[3]*mb[3];
        float d0 = ua[0]-ma[0], d1 = ua[1]-ma[1], d2 = ua[2]-ma[2], d3 = ua[3]-ma[3];
        float d4 = ub[0]-mb[0], d5 = ub[1]-mb[1], d6 = ub[2]-mb[2], d7 = ub[3]-mb[3];
        sd2 = fmaf(d0,d0,sd2); sd2 = fmaf(d1,d1,sd2); sd2 = fmaf(d2,d2,sd2); sd2 = fmaf(d3,d3,sd2);
        sd2 = fmaf(d4,d4,sd2); sd2 = fmaf(d5,d5,sd2); sd2 = fmaf(d6,d6,sd2); sd2 = fmaf(d7,d7,sd2);
        u4v ps, pd;
        ps[0] = cvtpk(s0,s1); ps[1] = cvtpk(s2,s3); ps[2] = cvtpk(s4,s5); ps[3] = cvtpk(s6,s7);
        pd[0] = cvtpk(d0,d1); pd[1] = cvtpk(d2,d3); pd[2] = cvtpk(d4,d5); pd[3] = cvtpk(d6,d7);
        s8v fs = __builtin_bit_cast(s8v, ps);
        s8v fd = __builtin_bit_cast(s8v, pd);

        // head MFMA with current bW (waits bW(c) only)
        accH = __builtin_amdgcn_mfma_f32_16x16x32_bf16(fs, bW, accH, 0, 0, 0);

        // prefetch chunk (c+1) mod 32 (wrap keeps pipeline uniform; buf^1)
        const int cn = (c + 1) & (NCHUNK - 1);
#pragma unroll
        for (int i = 0; i < 4; ++i)
            glds16(smem + (bsel ^ 1) * 16384 + w * 4096 + i * 1024,
                   gsrcW + (size_t)cn * 16384 + i * 1024);
        ua = *(const ff4*)(uR + cn * KC);
        ub = *(const ff4*)(uR + cn * KC + 4);
        ma = *(const ff4*)(mR + cn * KC);
        mb = *(const ff4*)(mR + cn * KC + 4);
        bW = *(const s8v*)(wrowB + cn * KC);
        __builtin_amdgcn_sched_barrier(0);

        // MFMA phase over chunk c (LDS reads only; prefetch stays in flight)
        const unsigned char* mbase = smem + bsel * 16384;
#pragma unroll
        for (int nt = 0; nt < 16; ++nt) {
            s8v bM = *(const s8v*)(mbase + nt * 1024 + myoff);
            accL[nt] = __builtin_amdgcn_mfma_f32_16x16x32_bf16(fs, bM, accL[nt], 0, 0, 0);
            accD[nt] = __builtin_amdgcn_mfma_f32_16x16x32_bf16(fd, bM, accD[nt], 0, 0, 0);
        }
        __builtin_amdgcn_sched_barrier(0);
    }

    // drain wrap-prefetch before aliasing sM with attn
    asm volatile("s_waitcnt vmcnt(0)" ::: "memory");
    __builtin_amdgcn_s_barrier();
    __builtin_amdgcn_sched_barrier(0);

    // ---- classification head (cols 0,1 live in lanes la=0,1) ----
    if (la < 2) {
#pragma unroll
        for (int j = 0; j < 4; ++j) {
            int gr = row0 + w * 16 + lb * 4 + j;
            out[1 + gr * 2 + la] = accH[j] + bout[la];
        }
    }
    // ---- ||d||^2 per row: reduce over the 4 lb col-groups ----
    sd2 += __shfl_xor(sd2, 16);
    sd2 += __shfl_xor(sd2, 32);   // every lane now holds row (l&15)'s total

    // ---- softmax over n (C layout: col=la, row=lb*4+j) ----
    float mr0, mr1, mr2, mr3;
    {
        ff4 mx = accL[0];
#pragma unroll
        for (int nt = 1; nt < 16; ++nt) {
            mx[0] = fmaxf(mx[0], accL[nt][0]); mx[1] = fmaxf(mx[1], accL[nt][1]);
            mx[2] = fmaxf(mx[2], accL[nt][2]); mx[3] = fmaxf(mx[3], accL[nt][3]);
        }
#pragma unroll
        for (int s = 1; s < 16; s <<= 1) {
            mx[0] = fmaxf(mx[0], __shfl_xor(mx[0], s));
            mx[1] = fmaxf(mx[1], __shfl_xor(mx[1], s));
            mx[2] = fmaxf(mx[2], __shfl_xor(mx[2], s));
            mx[3] = fmaxf(mx[3], __shfl_xor(mx[3], s));
        }
        mr0 = mx[0]; mr1 = mx[1]; mr2 = mx[2]; mr3 = mx[3];
    }
    ff4 sumv = (ff4)0.0f;
#pragma unroll
    for (int nt = 0; nt < 16; ++nt) {
        accL[nt][0] = __expf(accL[nt][0] - mr0);
        accL[nt][1] = __expf(accL[nt][1] - mr1);
        accL[nt][2] = __expf(accL[nt][2] - mr2);
        accL[nt][3] = __expf(accL[nt][3] - mr3);
        sumv[0] += accL[nt][0]; sumv[1] += accL[nt][1];
        sumv[2] += accL[nt][2]; sumv[3] += accL[nt][3];
    }
#pragma unroll
    for (int s = 1; s < 16; s <<= 1) {
        sumv[0] += __shfl_xor(sumv[0], s); sumv[1] += __shfl_xor(sumv[1], s);
        sumv[2] += __shfl_xor(sumv[2], s); sumv[3] += __shfl_xor(sumv[3], s);
    }
    const float i0v = 1.0f / sumv[0], i1v = 1.0f / sumv[1];
    const float i2v = 1.0f / sumv[2], i3v = 1.0f / sumv[3];
    ff4 cross = (ff4)0.0f;
#pragma unroll
    for (int nt = 0; nt < 16; ++nt) {
        accL[nt][0] *= i0v; accL[nt][1] *= i1v; accL[nt][2] *= i2v; accL[nt][3] *= i3v;
        cross[0] = fmaf(accL[nt][0], accD[nt][0], cross[0]);
        cross[1] = fmaf(accL[nt][1], accD[nt][1], cross[1]);
        cross[2] = fmaf(accL[nt][2], accD[nt][2], cross[2]);
        cross[3] = fmaf(accL[nt][3], accD[nt][3], cross[3]);
    }
#pragma unroll
    for (int s = 1; s < 16; s <<= 1) {
        cross[0] += __shfl_xor(cross[0], s); cross[1] += __shfl_xor(cross[1], s);
        cross[2] += __shfl_xor(cross[2], s); cross[3] += __shfl_xor(cross[3], s);
    }

    // ---- stage attn (bf16) to wave's 8KB LDS tile, XOR-swizzled (aliases sM) ----
    // ushort index: r*256 + ((nb ^ (r&7))<<3) + (n&7), nb = n>>3
    unsigned short* myAttn = sAttn + w * 4096;
    {
        const int rb = lb << 2;
        const int cl = la & 7;
#pragma unroll
        for (int nt = 0; nt < 16; ++nt) {
            const int nb = nt * 2 + (la >> 3);
            myAttn[(rb + 0) * 256 + ((nb ^ ((rb + 0) & 7)) << 3) + cl] = (unsigned short)bf16r(accL[nt][0]);
            myAttn[(rb + 1) * 256 + ((nb ^ ((rb + 1) & 7)) << 3) + cl] = (unsigned short)bf16r(accL[nt][1]);
            myAttn[(rb + 2) * 256 + ((nb ^ ((rb + 2) & 7)) << 3) + cl] = (unsigned short)bf16r(accL[nt][2]);
            myAttn[(rb + 3) * 256 + ((nb ^ ((rb + 3) & 7)) << 3) + cl] = (unsigned short)bf16r(accL[nt][3]);
        }
    }
    // same-wave LDS write->read: compiler handles lgkmcnt ordering

    // ---- gv = attn @ G (G symmetric -> row-major fragments valid as B) ----
    ff4 accG[16];
#pragma unroll
    for (int i = 0; i < 16; ++i) accG[i] = (ff4)0.0f;
#pragma unroll
    for (int ks = 0; ks < 8; ++ks) {
        const int ko = ks * 32 + (lb << 3);
        s8v aA = *(const s8v*)(myAttn + la * 256 + (((ks * 4 + lb) ^ (la & 7)) << 3));
#pragma unroll
        for (int nt = 0; nt < 16; ++nt) {
            s8v bG = *(const s8v*)(Gbf + (size_t)(nt * 16 + la) * Nn + ko);
            accG[nt] = __builtin_amdgcn_mfma_f32_16x16x32_bf16(aA, bG, accG[nt], 0, 0, 0);
        }
    }
    ff4 quad = (ff4)0.0f;
#pragma unroll
    for (int nt = 0; nt < 16; ++nt) {
        quad[0] = fmaf(accL[nt][0], accG[nt][0], quad[0]);
        quad[1] = fmaf(accL[nt][1], accG[nt][1], quad[1]);
        quad[2] = fmaf(accL[nt][2], accG[nt][2], quad[2]);
        quad[3] = fmaf(accL[nt][3], accG[nt][3], quad[3]);
    }
#pragma unroll
    for (int s = 1; s < 16; s <<= 1) {
        quad[0] += __shfl_xor(quad[0], s); quad[1] += __shfl_xor(quad[1], s);
        quad[2] += __shfl_xor(quad[2], s); quad[3] += __shfl_xor(quad[3], s);
    }

    // ---- score & per-wave loss partial ----
    float sdr = __shfl(sd2, (lb << 2) + la);   // row r = lb*4+la lives in lane r
    float val = 0.f;
    if (la < 4) {
        const int r = (lb << 2) + la;
        float cr = (la == 0) ? cross[0] : (la == 1) ? cross[1] : (la == 2) ? cross[2] : cross[3];
        float qd = (la == 0) ? quad[0]  : (la == 1) ? quad[1]  : (la == 2) ? quad[2]  : quad[3];
        float s2 = sdr + 2.0f * cr + qd;
        float sc = sqrtf(fmaxf(s2, 0.0f));
        const int gr = row0 + w * 16 + r;
        val = (float)(2 * label[gr] - 1) * sc;
    }
#pragma unroll
    for (int s = 1; s < 64; s <<= 1) val += __shfl_xor(val, s);
    if (l == 0) partials[blockIdx.x * 4 + w] = val;
}

// ---- deterministic final reduction of per-wave partials -> loss ----
__global__ void finalize_kernel(const float* __restrict__ partials, float* __restrict__ out,
                                int np, float invB) {
    const int t = threadIdx.x;
    float v = 0.f;
    for (int i = t; i < np; i += 256) v += partials[i];
#pragma unroll
    for (int s = 1; s < 64; s <<= 1) v += __shfl_xor(v, s);
    __shared__ float ws4[4];
    if ((t & 63) == 0) ws4[t >> 6] = v;
    __syncthreads();
    if (t == 0) out[0] = (ws4[0] + ws4[1] + ws4[2] + ws4[3]) * invB;
}

extern "C" void kernel_launch(void* const* d_in, const int* in_sizes, int n_in,
                              void* d_out, int out_size, void* d_ws, size_t ws_size,
                              hipStream_t stream) {
    const float* user  = (const float*)d_in[0];
    const float* music = (const float*)d_in[1];
    const float* mem   = (const float*)d_in[2];
    const float* Wout  = (const float*)d_in[3];
    const float* bout  = (const float*)d_in[4];
    const int*   label = (const int*)d_in[5];
    const int Bn   = in_sizes[0] / Hd;   // 65536
    const int nblk = Bn / 64;            // 1024

    unsigned short* memB = (unsigned short*)d_ws;                                  // 512 KB
    unsigned short* Wbf  = (unsigned short*)((char*)d_ws + 524288);                // 4 KB
    unsigned short* Gbf  = (unsigned short*)((char*)d_ws + 524288 + 4096);         // 128 KB
    float* partials      = (float*)((char*)d_ws + 524288 + 4096 + 131072);         // 16 KB

    conv_mem_kernel<<<128, 256, 0, stream>>>(mem, memB);
    conv_w_kernel<<<1, 256, 0, stream>>>(Wout, Wbf);
    gram_kernel<<<64, 256, 0, stream>>>(mem, Gbf);
    fused_kernel<<<nblk, 256, 0, stream>>>(user, music, bout, label, memB, Wbf, Gbf,
                                           (float*)d_out, partials);
    finalize_kernel<<<1, 256, 0, stream>>>(partials, (float*)d_out, nblk * 4, 1.0f / (float)Bn);
}

// Round 7
// 221.848 us; speedup vs baseline: 2.3973x; 2.3973x over previous
//
#include <hip/hip_runtime.h>
#include <hip/hip_bf16.h>

typedef float ff4 __attribute__((ext_vector_type(4)));
typedef short s8v __attribute__((ext_vector_type(8)));
typedef unsigned int u4v __attribute__((ext_vector_type(4)));
typedef unsigned int u2v __attribute__((ext_vector_type(2)));

#define Hd 1024
#define Nn 256
#define KC 32
#define NCHUNK 32
#define RB 32          // rows per block
#define SSTR 40        // sS/sD stride in ushorts (80 B, 16B-aligned, 2-way-free frag reads)

__device__ __forceinline__ unsigned bf16r(float f) {
    unsigned u = __builtin_bit_cast(unsigned, f);
    return (u + 0x7FFFu + ((u >> 16) & 1u)) >> 16;   // RNE f32->bf16
}

__device__ __forceinline__ unsigned cvtpk(float lo, float hi) {
    unsigned r;
    asm("v_cvt_pk_bf16_f32 %0, %1, %2" : "=v"(r) : "v"(lo), "v"(hi));
    return r;
}

__device__ __forceinline__ void glds16(void* lds, const void* g) {
    __builtin_amdgcn_global_load_lds(
        (const __attribute__((address_space(1))) unsigned int*)g,
        (__attribute__((address_space(3))) unsigned int*)lds, 16, 0, 0);
}

// ---- memB: chunk-major KC=32, 16B-block swizzled (verified R5):
// byte(c,r,b) at c*16384 + r*64 + ((b ^ ((r>>1)&3))*16) = bf16(mem[r][c*32 + b*8 .. +8])
__global__ void conv_mem_kernel(const float* __restrict__ mem, unsigned short* __restrict__ memB) {
    int g = blockIdx.x * 256 + threadIdx.x;   // 0..32767
    int b = g & 3;
    int r = (g >> 2) & 255;
    int c = g >> 10;
    const float* src = mem + (size_t)r * Hd + c * KC + b * 8;
    ff4 a0 = *(const ff4*)src;
    ff4 a1 = *(const ff4*)(src + 4);
    u4v v;
    v[0] = bf16r(a0[0]) | (bf16r(a0[1]) << 16);
    v[1] = bf16r(a0[2]) | (bf16r(a0[3]) << 16);
    v[2] = bf16r(a1[0]) | (bf16r(a1[1]) << 16);
    v[3] = bf16r(a1[2]) | (bf16r(a1[3]) << 16);
    size_t dst = (size_t)c * 16384 + (size_t)r * 64 + (size_t)((b ^ ((r >> 1) & 3)) * 16);
    *(u4v*)((char*)memB + dst) = v;
}

// ---- Wbf[c][h] = bf16(Wout[h][c]), c in {0,1} ----
__global__ void conv_w_kernel(const float* __restrict__ Wout, unsigned short* __restrict__ Wbf) {
    int t = threadIdx.x;
    int c = t >> 7;
    int h0 = (t & 127) * 8;
    u4v v;
#pragma unroll
    for (int j = 0; j < 4; ++j) {
        unsigned lo = bf16r(Wout[(h0 + 2 * j) * 2 + c]);
        unsigned hi = bf16r(Wout[(h0 + 2 * j + 1) * 2 + c]);
        v[j] = lo | (hi << 16);
    }
    *(u4v*)(Wbf + (size_t)c * Hd + h0) = v;
}

// ---- Gram matrix G = mem @ mem^T  [256][256], bf16 ----
__global__ __launch_bounds__(256) void gram_kernel(const float* __restrict__ mem,
                                                   unsigned short* __restrict__ Gbf) {
    __shared__ float LA[32][132];
    __shared__ float LB[32][132];
    const int t = threadIdx.x;
    const int bi = blockIdx.x >> 3, bj = blockIdx.x & 7;
    const int j = t & 31, i0 = t >> 5;
    float acc0 = 0.f, acc1 = 0.f, acc2 = 0.f, acc3 = 0.f;
    for (int kc = 0; kc < Hd; kc += 128) {
        __syncthreads();
#pragma unroll
        for (int q = 0; q < 4; ++q) {
            int c = t + q * 256;
            int r = c >> 5, fc = (c & 31) << 2;
            *(ff4*)&LA[r][fc] = *(const ff4*)(mem + (size_t)(bi * 32 + r) * Hd + kc + fc);
            *(ff4*)&LB[r][fc] = *(const ff4*)(mem + (size_t)(bj * 32 + r) * Hd + kc + fc);
        }
        __syncthreads();
#pragma unroll 4
        for (int kk = 0; kk < 128; kk += 4) {
            ff4 b = *(const ff4*)&LB[j][kk];
            ff4 a0 = *(const ff4*)&LA[i0][kk];
            ff4 a1 = *(const ff4*)&LA[i0 + 8][kk];
            ff4 a2 = *(const ff4*)&LA[i0 + 16][kk];
            ff4 a3 = *(const ff4*)&LA[i0 + 24][kk];
            acc0 += a0[0]*b[0] + a0[1]*b[1] + a0[2]*b[2] + a0[3]*b[3];
            acc1 += a1[0]*b[0] + a1[1]*b[1] + a1[2]*b[2] + a1[3]*b[3];
            acc2 += a2[0]*b[0] + a2[1]*b[1] + a2[2]*b[2] + a2[3]*b[3];
            acc3 += a3[0]*b[0] + a3[1]*b[1] + a3[2]*b[2] + a3[3]*b[3];
        }
    }
    const int gj = bj * 32 + j;
    Gbf[(size_t)(bi * 32 + i0 +  0) * Nn + gj] = (unsigned short)bf16r(acc0);
    Gbf[(size_t)(bi * 32 + i0 +  8) * Nn + gj] = (unsigned short)bf16r(acc1);
    Gbf[(size_t)(bi * 32 + i0 + 16) * Nn + gj] = (unsigned short)bf16r(acc2);
    Gbf[(size_t)(bi * 32 + i0 + 24) * Nn + gj] = (unsigned short)bf16r(acc3);
}

// ---- fused main kernel: 32 rows/block, 4 waves (2 row-groups x 2 col-halves) ----
// LDS (39168 B): [0,32768) sM dbuf; [32768,35328) sS; [35328,37888) sD;
//                [37888,39168) f32 scalars; epilogue sAttn[32][264] aliases [0,16896)
__global__ __launch_bounds__(256, 4) void fused_kernel(
    const float* __restrict__ user, const float* __restrict__ music,
    const float* __restrict__ bout, const int* __restrict__ label,
    const unsigned short* __restrict__ memB,   // [32][256][32] bf16, block-swizzled
    const unsigned short* __restrict__ Wbf,    // [2][1024] bf16
    const unsigned short* __restrict__ Gbf,    // [256][256] bf16
    float* __restrict__ out, float* __restrict__ partials)
{
    __shared__ __align__(16) unsigned char smem[39168];
    unsigned short* sS = (unsigned short*)(smem + 32768);
    unsigned short* sD = (unsigned short*)(smem + 35328);
    float* fMax   = (float*)(smem + 37888);        // [2][32]
    float* fSum   = fMax + 64;                     // [2][32]
    float* fCross = fMax + 128;                    // [2][32]
    float* fQuad  = fMax + 192;                    // [2][32]
    float* fAux   = fMax + 256;                    // [32]  ||d||^2
    unsigned short* sAttn = (unsigned short*)smem; // epilogue alias [32][264]

    const int t = threadIdx.x;
    const int w = t >> 6;
    const int l = t & 63;
    const int la = l & 15, lb = l >> 4;
    const int g = w >> 1;        // row-group (16 rows)
    const int h = w & 1;         // col-half (128 n)
    const int row0 = blockIdx.x * RB;

    // staging role: thread (sr, kp) handles row sr, cols kp*4..+4 of each chunk
    const int sr = t >> 3, kp = t & 7;
    const float* uR = user  + (size_t)(row0 + sr) * Hd + kp * 4;
    const float* mR = music + (size_t)(row0 + sr) * Hd + kp * 4;
    const char* gsrcW = (const char*)memB + w * 4096 + l * 16;
    const unsigned short* wrowB = Wbf + (size_t)(la < 2 ? la : 1) * Hd + lb * 8;

    const int arow = (g * 16 + la) * SSTR + lb * 8;           // fs/fd ushort offset
    const int moff = h * 8192 + la * 64 + ((lb ^ ((la >> 1) & 3)) << 4);  // bM byte off in buf

    ff4 accL[8], accD[8];
#pragma unroll
    for (int i = 0; i < 8; ++i) { accL[i] = (ff4)0.0f; accD[i] = (ff4)0.0f; }
    ff4 accH = (ff4)0.0f;
    float sd2 = 0.f;

    // ---- prologue: stage chunk 0 ----
#pragma unroll
    for (int i = 0; i < 4; ++i)
        glds16(smem + w * 4096 + i * 1024, gsrcW + i * 1024);
    {
        ff4 uv = *(const ff4*)(uR);
        ff4 mv = *(const ff4*)(mR);
        float d0 = uv[0]-mv[0], d1 = uv[1]-mv[1], d2 = uv[2]-mv[2], d3 = uv[3]-mv[3];
        sd2 = fmaf(d0,d0,sd2); sd2 = fmaf(d1,d1,sd2); sd2 = fmaf(d2,d2,sd2); sd2 = fmaf(d3,d3,sd2);
        u2v vs, vd;
        vs[0] = cvtpk(uv[0]*mv[0], uv[1]*mv[1]); vs[1] = cvtpk(uv[2]*mv[2], uv[3]*mv[3]);
        vd[0] = cvtpk(d0, d1);                   vd[1] = cvtpk(d2, d3);
        *(u2v*)(sS + sr * SSTR + kp * 4) = vs;
        *(u2v*)(sD + sr * SSTR + kp * 4) = vd;
    }
    __syncthreads();   // full drain: sM buf0 + sS/sD(0) ready

    for (int c = 0; c < NCHUNK; ++c) {
        const int p = c & 1;
        // read current A-frags before they get overwritten
        s8v fs = *(const s8v*)(sS + arow);
        s8v fd = *(const s8v*)(sD + arow);
        s8v bW = *(const s8v*)(wrowB + c * KC);
        ff4 nuv, nmv;
        if (c + 1 < NCHUNK) {
            // prefetch next chunk: mem tile to LDS buf p^1, u/m to regs
#pragma unroll
            for (int i = 0; i < 4; ++i)
                glds16(smem + (p ^ 1) * 16384 + w * 4096 + i * 1024,
                       gsrcW + (size_t)(c + 1) * 16384 + i * 1024);
            nuv = *(const ff4*)(uR + (c + 1) * KC);
            nmv = *(const ff4*)(mR + (c + 1) * KC);
        }
        __syncthreads();   // all waves done reading sS/sD(c); glds(c+1)+um landed (full drain)
        // MFMA over chunk c
        {
            const unsigned char* mbase = smem + p * 16384;
#pragma unroll
            for (int nt = 0; nt < 8; ++nt) {
                s8v bM = *(const s8v*)(mbase + nt * 1024 + moff);
                accL[nt] = __builtin_amdgcn_mfma_f32_16x16x32_bf16(fs, bM, accL[nt], 0, 0, 0);
                accD[nt] = __builtin_amdgcn_mfma_f32_16x16x32_bf16(fd, bM, accD[nt], 0, 0, 0);
            }
            accH = __builtin_amdgcn_mfma_f32_16x16x32_bf16(fs, bW, accH, 0, 0, 0);
        }
        // stage s/d for chunk c+1 (safe: reads of (c) completed at the sync above)
        if (c + 1 < NCHUNK) {
            float d0 = nuv[0]-nmv[0], d1 = nuv[1]-nmv[1], d2 = nuv[2]-nmv[2], d3 = nuv[3]-nmv[3];
            sd2 = fmaf(d0,d0,sd2); sd2 = fmaf(d1,d1,sd2); sd2 = fmaf(d2,d2,sd2); sd2 = fmaf(d3,d3,sd2);
            u2v vs, vd;
            vs[0] = cvtpk(nuv[0]*nmv[0], nuv[1]*nmv[1]); vs[1] = cvtpk(nuv[2]*nmv[2], nuv[3]*nmv[3]);
            vd[0] = cvtpk(d0, d1);                       vd[1] = cvtpk(d2, d3);
            *(u2v*)(sS + sr * SSTR + kp * 4) = vs;
            *(u2v*)(sD + sr * SSTR + kp * 4) = vd;
        }
        __syncthreads();   // sS/sD(c+1) + sM[p^1] visible for next iteration
    }

    // ---- classification head (cols 0,1 live in lanes la<2; h==0 waves store) ----
    if (h == 0 && la < 2) {
#pragma unroll
        for (int j = 0; j < 4; ++j) {
            int gr = row0 + g * 16 + lb * 4 + j;
            out[1 + gr * 2 + la] = accH[j] + bout[la];
        }
    }
    // ---- ||d||^2: reduce over 8 staging col-parts, write per-row ----
    sd2 += __shfl_xor(sd2, 1);
    sd2 += __shfl_xor(sd2, 2);
    sd2 += __shfl_xor(sd2, 4);
    if (kp == 0) fAux[sr] = sd2;

    // ---- half-softmax: local max & sumexp over this wave's 128 cols ----
    ff4 mx = accL[0];
#pragma unroll
    for (int nt = 1; nt < 8; ++nt) {
        mx[0] = fmaxf(mx[0], accL[nt][0]); mx[1] = fmaxf(mx[1], accL[nt][1]);
        mx[2] = fmaxf(mx[2], accL[nt][2]); mx[3] = fmaxf(mx[3], accL[nt][3]);
    }
#pragma unroll
    for (int s = 1; s < 16; s <<= 1) {
        mx[0] = fmaxf(mx[0], __shfl_xor(mx[0], s));
        mx[1] = fmaxf(mx[1], __shfl_xor(mx[1], s));
        mx[2] = fmaxf(mx[2], __shfl_xor(mx[2], s));
        mx[3] = fmaxf(mx[3], __shfl_xor(mx[3], s));
    }
    ff4 sm = (ff4)0.0f;
#pragma unroll
    for (int nt = 0; nt < 8; ++nt) {
        sm[0] += __expf(accL[nt][0] - mx[0]); sm[1] += __expf(accL[nt][1] - mx[1]);
        sm[2] += __expf(accL[nt][2] - mx[2]); sm[3] += __expf(accL[nt][3] - mx[3]);
    }
#pragma unroll
    for (int s = 1; s < 16; s <<= 1) {
        sm[0] += __shfl_xor(sm[0], s); sm[1] += __shfl_xor(sm[1], s);
        sm[2] += __shfl_xor(sm[2], s); sm[3] += __shfl_xor(sm[3], s);
    }
    if (la < 4) {
        const int grow = g * 16 + lb * 4 + la;
        float mv = (la == 0) ? mx[0] : (la == 1) ? mx[1] : (la == 2) ? mx[2] : mx[3];
        float sv = (la == 0) ? sm[0] : (la == 1) ? sm[1] : (la == 2) ? sm[2] : sm[3];
        fMax[h * 32 + grow] = mv;
        fSum[h * 32 + grow] = sv;
    }
    __syncthreads();   // fAux + fMax + fSum visible

    // ---- combine halves -> per-row M, 1/denom ----
    ff4 Mr, Dinv;
#pragma unroll
    for (int j = 0; j < 4; ++j) {
        const int grow = g * 16 + lb * 4 + j;
        float m0 = fMax[grow], m1 = fMax[32 + grow];
        float M = fmaxf(m0, m1);
        float den = fSum[grow] * __expf(m0 - M) + fSum[32 + grow] * __expf(m1 - M);
        Mr[j] = M; Dinv[j] = 1.0f / den;
    }
    // ---- attn + cross partial ----
    ff4 cross = (ff4)0.0f;
#pragma unroll
    for (int nt = 0; nt < 8; ++nt) {
        accL[nt][0] = __expf(accL[nt][0] - Mr[0]) * Dinv[0];
        accL[nt][1] = __expf(accL[nt][1] - Mr[1]) * Dinv[1];
        accL[nt][2] = __expf(accL[nt][2] - Mr[2]) * Dinv[2];
        accL[nt][3] = __expf(accL[nt][3] - Mr[3]) * Dinv[3];
        cross[0] = fmaf(accL[nt][0], accD[nt][0], cross[0]);
        cross[1] = fmaf(accL[nt][1], accD[nt][1], cross[1]);
        cross[2] = fmaf(accL[nt][2], accD[nt][2], cross[2]);
        cross[3] = fmaf(accL[nt][3], accD[nt][3], cross[3]);
    }
#pragma unroll
    for (int s = 1; s < 16; s <<= 1) {
        cross[0] += __shfl_xor(cross[0], s); cross[1] += __shfl_xor(cross[1], s);
        cross[2] += __shfl_xor(cross[2], s); cross[3] += __shfl_xor(cross[3], s);
    }
    if (la < 4) {
        const int grow = g * 16 + lb * 4 + la;
        float cv = (la == 0) ? cross[0] : (la == 1) ? cross[1] : (la == 2) ? cross[2] : cross[3];
        fCross[h * 32 + grow] = cv;
    }
    // ---- stage attn rows (bf16) to shared [32][264]; this wave's col-half ----
    {
        const int rb = lb << 2;
#pragma unroll
        for (int nt = 0; nt < 8; ++nt) {
            const int cc = h * 128 + nt * 16 + la;
            sAttn[(g * 16 + rb + 0) * 264 + cc] = (unsigned short)bf16r(accL[nt][0]);
            sAttn[(g * 16 + rb + 1) * 264 + cc] = (unsigned short)bf16r(accL[nt][1]);
            sAttn[(g * 16 + rb + 2) * 264 + cc] = (unsigned short)bf16r(accL[nt][2]);
            sAttn[(g * 16 + rb + 3) * 264 + cc] = (unsigned short)bf16r(accL[nt][3]);
        }
    }
    __syncthreads();   // fCross + full attn rows visible

    // ---- gv = attn @ G over this wave's 128 output cols (G symmetric) ----
    ff4 accG[8];
#pragma unroll
    for (int i = 0; i < 8; ++i) accG[i] = (ff4)0.0f;
#pragma unroll
    for (int ks = 0; ks < 8; ++ks) {
        s8v aA = *(const s8v*)(sAttn + (g * 16 + la) * 264 + ks * 32 + lb * 8);
#pragma unroll
        for (int nt = 0; nt < 8; ++nt) {
            s8v bG = *(const s8v*)(Gbf + (size_t)(h * 128 + nt * 16 + la) * Nn + ks * 32 + lb * 8);
            accG[nt] = __builtin_amdgcn_mfma_f32_16x16x32_bf16(aA, bG, accG[nt], 0, 0, 0);
        }
    }
    ff4 quad = (ff4)0.0f;
#pragma unroll
    for (int nt = 0; nt < 8; ++nt) {
        quad[0] = fmaf(accL[nt][0], accG[nt][0], quad[0]);
        quad[1] = fmaf(accL[nt][1], accG[nt][1], quad[1]);
        quad[2] = fmaf(accL[nt][2], accG[nt][2], quad[2]);
        quad[3] = fmaf(accL[nt][3], accG[nt][3], quad[3]);
    }
#pragma unroll
    for (int s = 1; s < 16; s <<= 1) {
        quad[0] += __shfl_xor(quad[0], s); quad[1] += __shfl_xor(quad[1], s);
        quad[2] += __shfl_xor(quad[2], s); quad[3] += __shfl_xor(quad[3], s);
    }
    if (la < 4) {
        const int grow = g * 16 + lb * 4 + la;
        float qv = (la == 0) ? quad[0] : (la == 1) ? quad[1] : (la == 2) ? quad[2] : quad[3];
        fQuad[h * 32 + grow] = qv;
    }
    __syncthreads();   // fQuad visible

    // ---- score & per-wave loss partial (h==0 waves only contribute) ----
    float val = 0.f;
    if (h == 0 && la < 4) {
        const int grow = g * 16 + lb * 4 + la;
        float s2 = fAux[grow] + 2.0f * (fCross[grow] + fCross[32 + grow])
                 + (fQuad[grow] + fQuad[32 + grow]);
        float sc = sqrtf(fmaxf(s2, 0.0f));
        const int gr = row0 + grow;
        val = (float)(2 * label[gr] - 1) * sc;
    }
#pragma unroll
    for (int s = 1; s < 64; s <<= 1) val += __shfl_xor(val, s);
    if (l == 0) partials[blockIdx.x * 4 + w] = val;   // h==1 waves write 0
}

// ---- deterministic final reduction of per-wave partials -> loss ----
__global__ void finalize_kernel(const float* __restrict__ partials, float* __restrict__ out,
                                int np, float invB) {
    const int t = threadIdx.x;
    float v = 0.f;
    for (int i = t; i < np; i += 256) v += partials[i];
#pragma unroll
    for (int s = 1; s < 64; s <<= 1) v += __shfl_xor(v, s);
    __shared__ float ws4[4];
    if ((t & 63) == 0) ws4[t >> 6] = v;
    __syncthreads();
    if (t == 0) out[0] = (ws4[0] + ws4[1] + ws4[2] + ws4[3]) * invB;
}

extern "C" void kernel_launch(void* const* d_in, const int* in_sizes, int n_in,
                              void* d_out, int out_size, void* d_ws, size_t ws_size,
                              hipStream_t stream) {
    const float* user  = (const float*)d_in[0];
    const float* music = (const float*)d_in[1];
    const float* mem   = (const float*)d_in[2];
    const float* Wout  = (const float*)d_in[3];
    const float* bout  = (const float*)d_in[4];
    const int*   label = (const int*)d_in[5];
    const int Bn   = in_sizes[0] / Hd;   // 65536
    const int nblk = Bn / RB;            // 2048

    unsigned short* memB = (unsigned short*)d_ws;                                  // 512 KB
    unsigned short* Wbf  = (unsigned short*)((char*)d_ws + 524288);                // 4 KB
    unsigned short* Gbf  = (unsigned short*)((char*)d_ws + 524288 + 4096);         // 128 KB
    float* partials      = (float*)((char*)d_ws + 524288 + 4096 + 131072);         // 32 KB

    conv_mem_kernel<<<128, 256, 0, stream>>>(mem, memB);
    conv_w_kernel<<<1, 256, 0, stream>>>(Wout, Wbf);
    gram_kernel<<<64, 256, 0, stream>>>(mem, Gbf);
    fused_kernel<<<nblk, 256, 0, stream>>>(user, music, bout, label, memB, Wbf, Gbf,
                                           (float*)d_out, partials);
    finalize_kernel<<<1, 256, 0, stream>>>(partials, (float*)d_out, nblk * 4, 1.0f / (float)Bn);
}